// Round 3
// baseline (498.640 us; speedup 1.0000x reference)
//
#include <hip/hip_runtime.h>
#include <hip/hip_bf16.h>
#include <stdint.h>

// Problem constants (B=4, T=1024, D=1024, E=8, HD=4096)
#define NE 8
#define DIM 1024
#define HDIM 4096
#define NTOK 4096
#define KSPLIT 4
#define MAXT 24     // max occupied 256-row m-tiles: 16 full + 8 partial
#define NT 16       // K-tiles of 64 per block (K=1024 for both gemms)

typedef unsigned short ushort_t;
typedef __attribute__((ext_vector_type(4))) float f32x4;
typedef __attribute__((ext_vector_type(8))) short bf16x8;
typedef __attribute__((ext_vector_type(8))) ushort_t u16x8;

#define WAITV(n) asm volatile("s_waitcnt vmcnt(" #n ")" ::: "memory")
#define WAITL0() asm volatile("s_waitcnt lgkmcnt(0)" ::: "memory")
#define SCHEDB() __builtin_amdgcn_sched_barrier(0)
#define BARRIER() __builtin_amdgcn_s_barrier()

// RNE float -> bf16 bits
__device__ __forceinline__ ushort_t f2b(float f) {
  union { float f; unsigned u; } c; c.f = f;
  unsigned u = c.u;
  return (ushort_t)((u + 0x7fffu + ((u >> 16) & 1u)) >> 16);
}

// truncate-pack 2 fp32 -> 2 bf16 in one dword via v_perm
__device__ __forceinline__ unsigned pk2(float a, float b) {
  union { float f; unsigned u; } x, y; x.f = a; y.f = b;
  return __builtin_amdgcn_perm(y.u, x.u, 0x07060302);
}

// async global->LDS, 16 bytes per lane; LDS dest = wave-uniform base + lane*16
__device__ __forceinline__ void gl2lds16(const void* g, void* l) {
  __builtin_amdgcn_global_load_lds(
      (__attribute__((address_space(1))) void*)g,
      (__attribute__((address_space(3))) void*)l, 16, 0, 0);
}

// MFMA quadrant: 4 M-frags x 2 N-frags x 2 k-slices = 16 MFMA (T5 setprio wrap)
#define PH_MFMA(mh, nh)                                                     \
  { __builtin_amdgcn_s_setprio(1);                                          \
    _Pragma("unroll")                                                       \
    for (int i2 = 0; i2 < 4; ++i2) {                                        \
      _Pragma("unroll")                                                     \
      for (int j2 = 0; j2 < 2; ++j2) {                                      \
        _Pragma("unroll")                                                   \
        for (int kk = 0; kk < 2; ++kk)                                      \
          acc[(mh)*4 + i2][(nh)*2 + j2] =                                   \
            __builtin_amdgcn_mfma_f32_16x16x32_bf16(                        \
              af[i2][kk], bf[(nh)*2 + j2][kk],                              \
              acc[(mh)*4 + i2][(nh)*2 + j2], 0, 0, 0);                      \
      }                                                                     \
    }                                                                       \
    __builtin_amdgcn_s_setprio(0); }

// frag loads; swizzled chunk index ck[] matches the staging-side involution
#define LOAD_AF(mh)                                                         \
  { _Pragma("unroll")                                                       \
    for (int i2 = 0; i2 < 4; ++i2) {                                        \
      _Pragma("unroll")                                                     \
      for (int kk = 0; kk < 2; ++kk)                                        \
        af[i2][kk] = *(const bf16x8*)&pA[aBase + ((mh)*64 + i2*16)*64 + ck[kk]]; \
    } }
#define LOAD_BF(nh)                                                         \
  { _Pragma("unroll")                                                       \
    for (int j2 = 0; j2 < 2; ++j2) {                                        \
      _Pragma("unroll")                                                     \
      for (int kk = 0; kk < 2; ++kk)                                        \
        bf[(nh)*2 + j2][kk] = *(const bf16x8*)&pB[bBase + (((nh)*2 + j2)*16)*64 + ck[kk]]; \
    } }

// ---------------- router: logits fp32 + argmax + count (fused) --------------
__global__ __launch_bounds__(256) void router_kernel(
    const float* __restrict__ x, const float* __restrict__ rw,
    int* __restrict__ eid, int* __restrict__ rank, int* __restrict__ cnt) {
  __shared__ float w[NE * 1028];
  for (int i = threadIdx.x; i < NE * DIM; i += 256) {
    int e = i >> 10, d = i & 1023;
    w[e * 1028 + d] = rw[i];
  }
  __syncthreads();
  int grp = threadIdx.x >> 3;
  int e = threadIdx.x & 7;
  int t = blockIdx.x * 32 + grp;
  const float4* xr = (const float4*)(x + (size_t)t * DIM);
  const float4* wr = (const float4*)(w + e * 1028);
  float acc = 0.f;
#pragma unroll 4
  for (int i = 0; i < DIM / 4; ++i) {
    float4 xv = xr[i], wv = wr[i];
    acc += xv.x * wv.x + xv.y * wv.y + xv.z * wv.z + xv.w * wv.w;
  }
  float v = acc; int ie = e;
#pragma unroll
  for (int m = 4; m; m >>= 1) {
    float ov = __shfl_xor(v, m, 8);
    int oi = __shfl_xor(ie, m, 8);
    if (ov > v || (ov == v && oi < ie)) { v = ov; ie = oi; }
  }
  if (e == 0) {
    eid[t] = ie;
    rank[t] = atomicAdd(&cnt[ie], 1);
  }
}

// prefix-sum + dense 256-row m-tile table
__global__ void scan_kernel(const int* __restrict__ cnt, int* __restrict__ offs,
                            int* __restrict__ tile_e, int* __restrict__ tile_m,
                            int* __restrict__ ntiles) {
  if (threadIdx.x == 0) {
    int s = 0, nt = 0;
    for (int e = 0; e < NE; ++e) {
      offs[e] = s;
      int c = cnt[e];
      for (int m = 0; m < c; m += 256) { tile_e[nt] = e; tile_m[nt] = m; ++nt; }
      s += c;
    }
    offs[NE] = s;
    *ntiles = nt;
  }
}

// one block per token: write sorted[] and gather x row -> bf16 grouped matrix
__global__ __launch_bounds__(256) void gather_kernel(
    const float* __restrict__ x, const int* __restrict__ eid,
    const int* __restrict__ rank, const int* __restrict__ offs,
    int* __restrict__ sorted, ushort_t* __restrict__ Xg) {
  int t = blockIdx.x;
  int e = eid[t];
  int pos = offs[e] + rank[t];
  if (threadIdx.x == 0) sorted[pos] = t;
  int i = threadIdx.x;
  float4 v = ((const float4*)(x + (size_t)t * DIM))[i];
  ushort4 o = make_ushort4(f2b(v.x), f2b(v.y), f2b(v.z), f2b(v.w));
  *(ushort4*)(Xg + (size_t)pos * DIM + i * 4) = o;
}

// ---------------- weight conversion ----------------------------------------
__global__ __launch_bounds__(256) void transpose_fc_kernel(
    const float* __restrict__ fc, ushort_t* __restrict__ fct) {
  __shared__ float tile[64][68];
  int e = blockIdx.z;
  int h0 = blockIdx.x * 64, d0 = blockIdx.y * 64;
  int tid = threadIdx.x;
  int rr = tid >> 4;
  int cc = (tid & 15) * 4;
  const float* src = fc + ((size_t)e * DIM + d0 + rr) * HDIM + h0 + cc;
#pragma unroll
  for (int i = 0; i < 4; ++i) {
    float4 v = *(const float4*)(src + (size_t)(i * 16) * HDIM);
    *(float4*)&tile[rr + i * 16][cc] = v;
  }
  __syncthreads();
  int hr = tid >> 2;
  int dseg = (tid & 3) * 16;
  union { ushort_t s[16]; u16x8 v[2]; } o;
#pragma unroll
  for (int j = 0; j < 16; ++j) o.s[j] = f2b(tile[dseg + j][hr]);
  ushort_t* dst = fct + ((size_t)e * HDIM + h0 + hr) * DIM + d0 + dseg;
  *(u16x8*)dst = o.v[0];
  *(u16x8*)(dst + 8) = o.v[1];
}

// ---------------- GEMM1: H = relu(Xg @ fct^T)^2, bf16 out -------------------
// 256x256 tile, BK=64, 8 waves (2Mx4N), per-wave 128x64 = 8x4 16x16x32 frags.
// 4-phase K-step: {AF0+BF0|MFMA M0N0}{BF1|MFMA M0N1}{AF1|MFMA M1N0}
// {stage T+2 + counted vmcnt(8)|MFMA M1N1}; 2 barriers/tile (publish, free).
// LDS XOR-swizzle (chunk ^= row&7) applied on gl2lds SOURCE + ds_read (T2).
__global__ __launch_bounds__(512, 2) void gemm1_kernel(
    const ushort_t* __restrict__ Xg, const ushort_t* __restrict__ fct,
    const int* __restrict__ offs, const int* __restrict__ tile_e,
    const int* __restrict__ tile_m, const int* __restrict__ ntiles,
    ushort_t* __restrict__ H) {
  __shared__ ushort_t As[2][16384];
  __shared__ ushort_t Bs[2][16384];

  // XCD swizzle: grid 16x24 = 384 = 48*8 (bijective)
  int lin = blockIdx.x + 16 * blockIdx.y;
  int sw = (lin & 7) * 48 + (lin >> 3);
  int bx = sw & 15, by = sw >> 4;
  if (by >= *ntiles) return;

  int e = tile_e[by];
  int mb = tile_m[by];
  int m0 = offs[e];
  int Me = offs[e + 1] - m0;
  int n0 = bx * 256;

  int tid = threadIdx.x;
  int wave = tid >> 6;
  int lane = tid & 63;
  int fr = lane & 15, kq = lane >> 4;
  int wr = wave & 1, wc = wave >> 1;

  // staging: thread covers 16B chunk q = c*512+tid; row=q>>3; pre-swizzled k
  int swk = ((tid & 7) ^ ((tid >> 3) & 7)) * 8;
  const ushort_t* aSrc[4]; const ushort_t* bSrc[4];
#pragma unroll
  for (int c = 0; c < 4; ++c) {
    int r = c * 64 + (tid >> 3);
    int rg = mb + r; if (rg >= Me) rg = Me - 1;   // clamp tail rows
    aSrc[c] = Xg + (size_t)(m0 + rg) * DIM + swk;
    bSrc[c] = fct + ((size_t)e * HDIM + n0 + r) * DIM + swk;
  }
  int sdst = wave * 512;

  int aBase = (wr * 128 + fr) * 64;
  int bBase = (wc * 64 + fr) * 64;
  int ck[2] = { (kq ^ (fr & 7)) * 8, ((4 + kq) ^ (fr & 7)) * 8 };

  f32x4 acc[8][4] = {};
  bf16x8 af[4][2], bf[4][2];

  auto stage = [&](int p, int X) __attribute__((always_inline)) {
    int ko = X * 64;
#pragma unroll
    for (int c = 0; c < 4; ++c)
      gl2lds16(aSrc[c] + ko, &As[p][c * 4096 + sdst]);
#pragma unroll
    for (int c = 0; c < 4; ++c)
      gl2lds16(bSrc[c] + ko, &Bs[p][c * 4096 + sdst]);
  };

  // prologue: tiles 0,1 in flight; retire tile 0 (8 newest stay in flight)
  stage(0, 0);
  stage(1, 1);
  WAITV(8);

  for (int T = 0; T < NT; ++T) {
    const int p = T & 1;
    const ushort_t* pA = As[p];
    const ushort_t* pB = Bs[p];
    BARRIER(); SCHEDB();                 // publish tile T
    LOAD_AF(0); LOAD_BF(0);              // 12 ds_read_b128
    WAITL0(); SCHEDB();
    PH_MFMA(0, 0);
    LOAD_BF(1);
    WAITL0(); SCHEDB();
    PH_MFMA(0, 1);
    LOAD_AF(1);
    WAITL0(); SCHEDB();
    PH_MFMA(1, 0);
    BARRIER(); SCHEDB();                 // all waves done reading tile T
    if (T + 2 < NT) { stage(p, T + 2); WAITV(8); }  // retire T+1, T+2 in flight
    else if (T + 1 < NT) { WAITV(0); }              // tail: retire T+1
    PH_MFMA(1, 1);
  }

  int cq = kq * 4;
#pragma unroll
  for (int i = 0; i < 8; ++i) {
#pragma unroll
    for (int r = 0; r < 4; ++r) {
      int rl = wr * 128 + i * 16 + cq + r;
      int rg = mb + rl;
      if (rg < Me) {
        ushort_t* dst = H + (size_t)(m0 + rg) * HDIM + n0 + wc * 64 + fr;
#pragma unroll
        for (int j = 0; j < 4; ++j) {
          float v = acc[i][j][r];
          v = fmaxf(v, 0.f);
          dst[j * 16] = f2b(v * v);
        }
      }
    }
  }
}

// ---------------- GEMM2: P[ks] = H @ proj^T (K-slice), no atomics -----------
// Same 256x256 4-phase structure. B (pj fp32) reg-staged: loads for tile T+1
// issued at ph1 (T14 issue-early), packed+ds_written at ph4 after the counted
// vmcnt (write-late), into swizzled LDS addresses (write-side of T2).
__global__ __launch_bounds__(512, 2) void gemm2_kernel(
    const ushort_t* __restrict__ Hm, const float* __restrict__ pj,
    const int* __restrict__ offs, const int* __restrict__ tile_e,
    const int* __restrict__ tile_m, const int* __restrict__ ntiles,
    float* __restrict__ P) {
  __shared__ ushort_t As[2][16384];
  __shared__ ushort_t Bs[2][16384];

  // XCD swizzle: grid 4x24x4 = 384
  int lin = blockIdx.x + 4 * (blockIdx.y + MAXT * blockIdx.z);
  int sw = (lin & 7) * 48 + (lin >> 3);
  int bx = sw & 3;
  int t2 = sw >> 2;
  int by = t2 % MAXT, bz = t2 / MAXT;
  if (by >= *ntiles) return;

  int e = tile_e[by];
  int mb = tile_m[by];
  int ks = bz;
  int m0 = offs[e];
  int Me = offs[e + 1] - m0;
  int n0 = bx * 256;
  int kbeg = ks * (HDIM / KSPLIT);

  int tid = threadIdx.x;
  int wave = tid >> 6;
  int lane = tid & 63;
  int fr = lane & 15, kq = lane >> 4;
  int wr = wave & 1, wc = wave >> 1;

  int swk = ((tid & 7) ^ ((tid >> 3) & 7)) * 8;
  const ushort_t* aSrc[4];
  const float* bSrc[4];
  int bDst[4];
#pragma unroll
  for (int c = 0; c < 4; ++c) {
    int r = c * 64 + (tid >> 3);
    int rg = mb + r; if (rg >= Me) rg = Me - 1;
    aSrc[c] = Hm + (size_t)(m0 + rg) * HDIM + kbeg + swk;
    bSrc[c] = pj + ((size_t)e * DIM + n0 + r) * HDIM + kbeg + (tid & 7) * 8;
    bDst[c] = r * 64 + swk;            // swizzled LDS write addr (ushorts)
  }
  int sdst = wave * 512;

  int aBase = (wr * 128 + fr) * 64;
  int bBase = (wc * 64 + fr) * 64;
  int ck[2] = { (kq ^ (fr & 7)) * 8, ((4 + kq) ^ (fr & 7)) * 8 };

  f32x4 acc[8][4] = {};
  bf16x8 af[4][2], bf[4][2];
  float4 bv[8];

  auto loadB = [&](int X) __attribute__((always_inline)) {
    int ko = X * 64;
#pragma unroll
    for (int c = 0; c < 4; ++c) {
      bv[2 * c]     = *(const float4*)(bSrc[c] + ko);
      bv[2 * c + 1] = *(const float4*)(bSrc[c] + ko + 4);
    }
  };
  auto writeB = [&](int pb) __attribute__((always_inline)) {
#pragma unroll
    for (int c = 0; c < 4; ++c) {
      union { unsigned u[4]; bf16x8 v; } w;
      w.u[0] = pk2(bv[2*c].x, bv[2*c].y);     w.u[1] = pk2(bv[2*c].z, bv[2*c].w);
      w.u[2] = pk2(bv[2*c+1].x, bv[2*c+1].y); w.u[3] = pk2(bv[2*c+1].z, bv[2*c+1].w);
      *(bf16x8*)&Bs[pb][bDst[c]] = w.v;
    }
  };
  auto stageA = [&](int p, int X) __attribute__((always_inline)) {
    int ko = X * 64;
#pragma unroll
    for (int c = 0; c < 4; ++c)
      gl2lds16(aSrc[c] + ko, &As[p][c * 4096 + sdst]);
  };

  // prologue: B0,B1 loaded+written; A0,A1 staged (A1's 4 stay in flight)
  loadB(0); stageA(0, 0);
  WAITV(4);                 // retire B0's 8 (A0's 4 in flight)
  writeB(0);
  loadB(1); stageA(1, 1);
  WAITV(4);                 // retire A0 + B1 (A1 in flight)
  writeB(1);
  WAITL0();

  for (int T = 0; T < NT; ++T) {
    const int p = T & 1;
    const ushort_t* pA = As[p];
    const ushort_t* pB = Bs[p];
    BARRIER(); SCHEDB();                 // publish tile T
    if (T >= 1 && T + 1 < NT) loadB(T + 1);   // issue-early (regs free since T-1 ph4)
    LOAD_AF(0); LOAD_BF(0);
    WAITL0(); SCHEDB();
    PH_MFMA(0, 0);
    LOAD_BF(1);
    WAITL0(); SCHEDB();
    PH_MFMA(0, 1);
    LOAD_AF(1);
    WAITL0(); SCHEDB();
    PH_MFMA(1, 0);
    BARRIER(); SCHEDB();                 // tile T fully consumed
    if (T + 2 < NT) stageA(p, T + 2);
    if (T + 1 < NT) { if (T + 2 < NT) { WAITV(4); } else { WAITV(0); } }
    if (T >= 1 && T + 1 < NT) { writeB(p ^ 1); WAITL0(); }  // write-late
    PH_MFMA(1, 1);
  }

  int cq = kq * 4;
#pragma unroll
  for (int i = 0; i < 8; ++i) {
#pragma unroll
    for (int r = 0; r < 4; ++r) {
      int rl = wr * 128 + i * 16 + cq + r;
      int rg = mb + rl;
      if (rg < Me) {
        float* dst = P + ((size_t)ks * NTOK + (m0 + rg)) * DIM + n0 + wc * 64 + fr;
#pragma unroll
        for (int j = 0; j < 4; ++j) dst[j * 16] = acc[i][j][r];
      }
    }
  }
}

// ---------------- reduce: out[tok] = sum_ks P[ks][pos], coalesced -----------
__global__ __launch_bounds__(256) void reduce_kernel(
    const float* __restrict__ P, const int* __restrict__ sorted,
    float* __restrict__ out) {
  int pos = blockIdx.x;
  int tok = sorted[pos];
  int i = threadIdx.x;
  size_t base = (size_t)pos * DIM + i * 4;
  const size_t S = (size_t)NTOK * DIM;
  f32x4 s = *(const f32x4*)(P + base) + *(const f32x4*)(P + S + base) +
            *(const f32x4*)(P + 2 * S + base) + *(const f32x4*)(P + 3 * S + base);
  *(f32x4*)(out + (size_t)tok * DIM + i * 4) = s;
}

// ---------------- launch -----------------------------------------------------
extern "C" void kernel_launch(void* const* d_in, const int* in_sizes, int n_in,
                              void* d_out, int out_size, void* d_ws, size_t ws_size,
                              hipStream_t stream) {
  const float* x  = (const float*)d_in[0];
  const float* rw = (const float*)d_in[1];
  const float* fc = (const float*)d_in[2];
  const float* pj = (const float*)d_in[3];
  float* out = (float*)d_out;
  char* ws = (char*)d_ws;

  // workspace layout (~106 MiB, same footprint as prior rounds)
  int* eid        = (int*)(ws + 0x0000);
  int* rank       = (int*)(ws + 0x4000);
  int* cnt        = (int*)(ws + 0x8000);
  int* offs       = (int*)(ws + 0x8100);
  int* tile_e     = (int*)(ws + 0x8200);
  int* tile_m     = (int*)(ws + 0x8600);
  int* ntiles     = (int*)(ws + 0x8a00);
  int* sorted     = (int*)(ws + 0x9000);
  ushort_t* Xg    = (ushort_t*)(ws + 0x10000);    // 8MB  [4096][1024] bf16
  ushort_t* H     = (ushort_t*)(ws + 0x810000);   // 32MB [4096][4096] bf16
  ushort_t* W     = (ushort_t*)(ws + 0x2810000);  // 64MB: fct (gemm1), then P
  float* P        = (float*)W;                    // fct dead after gemm1

  hipMemsetAsync(cnt, 0, 32, stream);
  router_kernel<<<NTOK / 32, 256, 0, stream>>>(x, rw, eid, rank, cnt);
  scan_kernel<<<1, 64, 0, stream>>>(cnt, offs, tile_e, tile_m, ntiles);
  gather_kernel<<<NTOK, 256, 0, stream>>>(x, eid, rank, offs, sorted, Xg);
  transpose_fc_kernel<<<dim3(HDIM / 64, DIM / 64, NE), 256, 0, stream>>>(fc, W);
  gemm1_kernel<<<dim3(HDIM / 256, MAXT), 512, 0, stream>>>(Xg, W, offs, tile_e, tile_m, ntiles, H);
  gemm2_kernel<<<dim3(DIM / 256, MAXT, KSPLIT), 512, 0, stream>>>(H, pj, offs, tile_e, tile_m, ntiles, P);
  reduce_kernel<<<NTOK, 256, 0, stream>>>(P, sorted, out);
}